// Round 8
// baseline (173.485 us; speedup 1.0000x reference)
//
#include <hip/hip_runtime.h>
#include <hip/hip_fp16.h>

// GCN 2-layer: N=50000 nodes, E=800000 edges, 128 -> 128(relu) -> 64
// R20: R19 correctness fix. R19 dropped edges: deg[] is the TRUE degree, and
//      the super-burst conditions (jend>=32 etc.) rounded DOWN, so d=20 only
//      consumed 16 rows (R17/R18's "b*16 < jend" rounded UP). Fix: iterate
//      the PADDED degree dp=(d+15)&~15 -> jend in {16,32,48,64} exactly and
//      the burst structure consumes exactly jend rows (sentinels contribute
//      zero: dinv[N]=0 in fused, zeroed hs2 row in agg64). Accumulate order
//      per real row identical to R18 -> absmax 0.001953125 exactly.
//      R19 model now gets a clean test: gather cost = waits*latency +
//      rows*issue; pad-16 keeps rows at 23.4/node, 32-row super-bursts give
//      ONE gather wait for d<=32 (99.99% of nodes).
// Evidence log: R2 MLP depth win; R4/R9 sliced layouts dead; R11 sentinel pad
// win; R12 fusion killed 51MB x2 trip; R13 spill catastrophe (min-waves cap +
// fat buffers); R14 shfl-idx ds_bpermute serialization; R15 branchy 2-node
// interleave dead; R16 uniform-row gather WIN (183.6->174.4; readlane ->
// scalar-base whole-wave row reads); R17 pad-16 neutral (rows down, waits up
// -> cancel); R18 chain compression WIN (175.0->168.7: dinv deferred via
// s_load, gemm1 merged into scatter launch); R19 edge-drop bug (round-down
// consume vs true degree). Harness poison fills (~44us each) own per-kernel
// top-5 -> judge by total.

#define N_NODES 50000
#define N_EDGES 800000
#define BINW    128
#define NBIN    391                    // ceil(50000/128)
#define CAP     2560                   // mean bin load 2046, ~11 sigma margin
#define CAP2    6656                   // padded: up to 2560 + 128*15 = 4480 fits
#define B_CHUNK 2048
#define NB_SCAT ((N_EDGES + B_CHUNK - 1) / B_CHUNK)   // 391
#define NB_GEMM ((N_NODES + 63) / 64)                 // 782

typedef __bf16 bf16x8 __attribute__((ext_vector_type(8)));
typedef float  f32x4  __attribute__((ext_vector_type(4)));

// ---------------- prep: W-frags, zero gcur, zero sentinel rows + dinv[N] ----------
template<int N>
__device__ inline void wprep_body(const float* __restrict__ W,
                                  __bf16* __restrict__ hi, __bf16* __restrict__ lo,
                                  int idx) {
    if (idx >= (N / 16) * 4 * 64) return;
    int l = idx & 63;
    int s = (idx >> 6) & 3;
    int c = idx >> 8;
    int n = c * 16 + (l & 15);
    int k0 = s * 32 + (l >> 4) * 8;
#pragma unroll
    for (int j = 0; j < 8; j++) {
        float w = W[(k0 + j) * N + n];
        __bf16 h = (__bf16)w;
        hi[idx * 8 + j] = h;
        lo[idx * 8 + j] = (__bf16)(w - (float)h);
    }
}

__global__ __launch_bounds__(256) void prep_kernel(
        const float* __restrict__ W1, const float* __restrict__ W2,
        __bf16* __restrict__ w1hi, __bf16* __restrict__ w1lo,
        __bf16* __restrict__ w2hi, __bf16* __restrict__ w2lo,
        int* __restrict__ gcur, __half* __restrict__ hs1, __half* __restrict__ hs2,
        float* __restrict__ dinv) {
    int b = blockIdx.x, tid = threadIdx.x;
    if (b < 8)       wprep_body<128>(W1, w1hi, w1lo, b * 256 + tid);
    else if (b < 12) wprep_body<64> (W2, w2hi, w2lo, (b - 8) * 256 + tid);
    else {
        for (int i = tid; i < NBIN; i += 256) gcur[i] = 0;
        if (tid < 128) hs1[(size_t)N_NODES * 128 + tid] = __float2half(0.f);
        if (tid < 64)  hs2[(size_t)N_NODES * 64 + tid] = __float2half(0.f);
        if (tid == 0)  dinv[N_NODES] = 0.f;       // sentinel weight (R18)
    }
}

// ---------------- MERGED: bin_scatter (blocks 0..390) || gemm1 (blocks 391..) -----

__device__ inline void bin_scatter_body(
        const int* __restrict__ src, const int* __restrict__ dst,
        int* __restrict__ gcur, unsigned* __restrict__ ebin) {
    __shared__ int cnt[512];
    __shared__ int boff[512];
    __shared__ int bcur[512];
    __shared__ int gbase[512];
    __shared__ unsigned stage[B_CHUNK];
    __shared__ int ex[256];
    int tid = threadIdx.x;
    int e0 = blockIdx.x * B_CHUNK;

    cnt[tid] = 0; cnt[tid + 256] = 0;
    __syncthreads();

    unsigned key[8]; int bins[8];
#pragma unroll
    for (int i = 0; i < 8; i++) {
        int e = e0 + tid + i * 256;               // coalesced
        if (e < N_EDGES) {
            int d = dst[e], s = src[e];
            key[i]  = ((unsigned)d << 16) | (unsigned)s;
            bins[i] = d >> 7;
            atomicAdd(&cnt[bins[i]], 1);
        } else bins[i] = -1;
    }
    __syncthreads();

    // exclusive scan of 512 bin counts with 256 threads (2 bins each)
    int a = cnt[2 * tid], b = cnt[2 * tid + 1];
    ex[tid] = a + b;
    __syncthreads();
    for (int off = 1; off < 256; off <<= 1) {
        int t = (tid >= off) ? ex[tid - off] : 0;
        __syncthreads();
        ex[tid] += t;
        __syncthreads();
    }
    int myex = ex[tid] - (a + b);
    boff[2 * tid] = myex;     boff[2 * tid + 1] = myex + a;
    bcur[2 * tid] = myex;     bcur[2 * tid + 1] = myex + a;
    __syncthreads();

    // compact into bin-contiguous staging
#pragma unroll
    for (int i = 0; i < 8; i++) {
        if (bins[i] >= 0) {
            int p = atomicAdd(&bcur[bins[i]], 1);
            stage[p] = key[i];
        }
    }

    // bulk-reserve global bin space (one atomic per non-empty (block,bin))
    __syncthreads();
    for (int b2 = tid; b2 < NBIN; b2 += 256) {
        int c = cnt[b2];
        gbase[b2] = (c > 0) ? atomicAdd(&gcur[b2], c) : 0;
    }
    __syncthreads();

    int total = N_EDGES - e0; if (total > B_CHUNK) total = B_CHUNK;
    for (int i = tid; i < total; i += 256) {
        unsigned k = stage[i];
        int bin = (int)(k >> 23);                 // dst>>7
        int idx = gbase[bin] + (i - boff[bin]);
        if (idx < CAP) ebin[(size_t)bin * CAP + idx] = k;  // guard (11-sigma)
    }
}

// gemm1 body: hs1[row][128] = fp16( (X@W1)[row] )  — UNSCALED (R18 defer)
__device__ inline void gemm_mfma128_body(
        int gb, const float* __restrict__ X, const __bf16* __restrict__ Whi,
        const __bf16* __restrict__ Wlo, __half* __restrict__ hs) {
    constexpr int NC = 8;
    int tid = threadIdx.x;
    int w = tid >> 6, lane = tid & 63;
    int q = lane >> 4, lr = lane & 15;
    int rb = gb * 64 + w * 16;
    int row = rb + lr;
    int rowc = (row < N_NODES) ? row : (N_NODES - 1);

    f32x4 acc[NC];
#pragma unroll
    for (int c = 0; c < NC; c++) acc[c] = (f32x4){0.f, 0.f, 0.f, 0.f};

#pragma unroll
    for (int s = 0; s < 4; s++) {
        const float* xp = X + (size_t)rowc * 128 + s * 32 + q * 8;
        float4 x0 = *(const float4*)xp;
        float4 x1 = *(const float4*)(xp + 4);
        float xv[8] = {x0.x, x0.y, x0.z, x0.w, x1.x, x1.y, x1.z, x1.w};
        bf16x8 a_hi, a_lo;
#pragma unroll
        for (int j = 0; j < 8; j++) {
            __bf16 h = (__bf16)xv[j];
            a_hi[j] = h;
            a_lo[j] = (__bf16)(xv[j] - (float)h);
        }
#pragma unroll
        for (int c = 0; c < NC; c++) {
            size_t fo = (size_t)((c * 4 + s) * 64 + lane) * 8;
            bf16x8 bh = *(const bf16x8*)(Whi + fo);
            bf16x8 bl = *(const bf16x8*)(Wlo + fo);
            acc[c] = __builtin_amdgcn_mfma_f32_16x16x32_bf16(a_hi, bh, acc[c], 0, 0, 0);
            acc[c] = __builtin_amdgcn_mfma_f32_16x16x32_bf16(a_lo, bh, acc[c], 0, 0, 0);
            acc[c] = __builtin_amdgcn_mfma_f32_16x16x32_bf16(a_hi, bl, acc[c], 0, 0, 0);
        }
    }

    // C/D layout: col = c*16 + lr, row(within 16) = q*4 + r
#pragma unroll
    for (int r = 0; r < 4; r++) {
        int grow = rb + q * 4 + r;
        if (grow < N_NODES) {
#pragma unroll
            for (int c = 0; c < NC; c++) {
                hs[(size_t)grow * 128 + c * 16 + lr] = __float2half(acc[c][r]);
            }
        }
    }
}

__global__ __launch_bounds__(256) void scatter_gemm_kernel(
        const int* __restrict__ src, const int* __restrict__ dst,
        int* __restrict__ gcur, unsigned* __restrict__ ebin,
        const float* __restrict__ X, const __bf16* __restrict__ Whi,
        const __bf16* __restrict__ Wlo, __half* __restrict__ hs1) {
    if (blockIdx.x < NB_SCAT) bin_scatter_body(src, dst, gcur, ebin);
    else gemm_mfma128_body(blockIdx.x - NB_SCAT, X, Whi, Wlo, hs1);
}

// ---------------- bin_build: histogram + padded scan + sentinel fill ---------------
// pad-16; sentinel prefill int4-vectorized.
__global__ __launch_bounds__(256) void bin_build_kernel(
        const unsigned* __restrict__ ebin, const int* __restrict__ gcur,
        int* __restrict__ deg, int* __restrict__ row_off,
        float* __restrict__ dinv, int* __restrict__ ssrc) {
    __shared__ int dl[BINW];
    __shared__ int pref[BINW];
    __shared__ int cur[BINW];
    __shared__ int padTotal;
    int bin = blockIdx.x, tid = threadIdx.x;
    if (tid < BINW) dl[tid] = 0;
    __syncthreads();
    int cnt = gcur[bin]; if (cnt > CAP) cnt = CAP;
    const unsigned* eb = ebin + (size_t)bin * CAP;
    for (int i = tid; i < cnt; i += 256)
        atomicAdd(&dl[(eb[i] >> 16) & 127], 1);
    __syncthreads();
    // Hillis-Steele inclusive scan over 128 PADDED counts (pad-16)
    int pc = 0;
    if (tid < BINW) { pc = (dl[tid] + 15) & ~15; pref[tid] = pc; }
    __syncthreads();
    for (int off = 1; off < BINW; off <<= 1) {
        int t = 0;
        if (tid < BINW && tid >= off) t = pref[tid - off];
        __syncthreads();
        if (tid < BINW) pref[tid] += t;
        __syncthreads();
    }
    if (tid < BINW) {
        int ex = pref[tid] - pc;                  // padded exclusive prefix
        cur[tid] = ex;
        int node = bin * BINW + tid;
        if (node < N_NODES) {
            deg[node]     = dl[tid];
            row_off[node] = bin * CAP2 + ex;
            dinv[node]    = rsqrtf((float)(dl[tid] + 1));   // +1 self-loop
        }
        if (tid == BINW - 1) padTotal = pref[tid];
    }
    __syncthreads();
    int pt4 = padTotal >> 2;                      // padTotal multiple of 16
    int4* sb4 = (int4*)(ssrc + (size_t)bin * CAP2);
    int4 sent = make_int4(N_NODES, N_NODES, N_NODES, N_NODES);
    for (int i = tid; i < pt4; i += 256) sb4[i] = sent;     // sentinel prefill
    __syncthreads();
    int* sb = ssrc + (size_t)bin * CAP2;
    for (int i = tid; i < cnt; i += 256) {
        unsigned k = eb[i];
        int p = atomicAdd(&cur[(k >> 16) & 127], 1);
        sb[p] = (int)(k & 0xFFFFu);
    }
}

// ---------------- FUSED: agg128(+relu) -> LDS x2 rows -> 16x64 MFMA -> hs2 --------
// block = 1024 thr = 16 waves = 16 nodes (50000 = 3125*16 exact).
// R20 gather: PADDED degree dp drives the loop; 32-row super-bursts +
// 16-tail (jend in {16,32,48,64}). One idx wait + one gather wait for
// dp<=32. Sentinel rows: weight dinv[N]=0.
__global__ __launch_bounds__(1024) void fused_agg_gemm_kernel(
        const __half* __restrict__ hs1, const int* __restrict__ row_off,
        const int* __restrict__ deg, const int* __restrict__ ssrc,
        const float* __restrict__ dinv, const float* __restrict__ bias,
        const __bf16* __restrict__ w2hi, const __bf16* __restrict__ w2lo,
        __half* __restrict__ hs2) {
    __shared__ float x2buf[16][132];              // pad 132: 2-way banks (free)
    int wave = threadIdx.x >> 6;
    int lane = threadIdx.x & 63;
    int rb = blockIdx.x * 16;
    int node = rb + wave;                         // always < N_NODES

    int beg = __builtin_amdgcn_readfirstlane(row_off[node]);
    int d   = __builtin_amdgcn_readfirstlane(deg[node]);
    int dp  = (d + 15) & ~15;                     // PADDED trip count (R20 fix)
    float di = dinv[node];
    const char* Hb = (const char*)hs1;            // row stride 256B
    float ax = 0.f, ay = 0.f;                     // lane owns ch 2*lane, 2*lane+1

    for (int jj = 0; jj < dp; jj += 64) {         // 64 edges per idx load
        int s_all = ssrc[beg + jj + lane];        // coalesced; span padded-16
        int jend = dp - jj; if (jend > 64) jend = 64;   // in {16,32,48,64}
        int done = 0;
        if (jend >= 32) {                         // super-burst 0: rows 0..31
            unsigned vv[32]; float ws[32];
#pragma unroll
            for (int u = 0; u < 32; u++) {
                int su = __builtin_amdgcn_readlane(s_all, u);
                vv[u] = *(const unsigned*)(Hb + (size_t)su * 256 + lane * 4);
                ws[u] = dinv[su];                 // uniform -> s_load (SGPR)
            }
#pragma unroll
            for (int u = 0; u < 32; u++) {
                float2 f = __half22float2(*(const __half2*)&vv[u]);
                ax = fmaf(ws[u], f.x, ax);
                ay = fmaf(ws[u], f.y, ay);
            }
            done = 32;
            if (jend >= 64) {                     // super-burst 1: rows 32..63
                unsigned v2[32]; float w2[32];
#pragma unroll
                for (int u = 0; u < 32; u++) {
                    int su = __builtin_amdgcn_readlane(s_all, 32 + u);
                    v2[u] = *(const unsigned*)(Hb + (size_t)su * 256 + lane * 4);
                    w2[u] = dinv[su];
                }
#pragma unroll
                for (int u = 0; u < 32; u++) {
                    float2 f = __half22float2(*(const __half2*)&v2[u]);
                    ax = fmaf(w2[u], f.x, ax);
                    ay = fmaf(w2[u], f.y, ay);
                }
                done = 64;
            }
        }
        if (jend - done >= 16) {                  // 16-tail (jend=16 or 48)
            unsigned vv[16]; float ws[16];
#pragma unroll
            for (int u = 0; u < 16; u++) {
                int su = __builtin_amdgcn_readlane(s_all, done + u);
                vv[u] = *(const unsigned*)(Hb + (size_t)su * 256 + lane * 4);
                ws[u] = dinv[su];
            }
#pragma unroll
            for (int u = 0; u < 16; u++) {
                float2 f = __half22float2(*(const __half2*)&vv[u]);
                ax = fmaf(ws[u], f.x, ax);
                ay = fmaf(ws[u], f.y, ay);
            }
        }
    }

    // epilogue: self-loop (di^2 * h[node]) + bias + relu, per-lane ch pair
    float2 sf = __half22float2(((const __half2*)(Hb + (size_t)node * 256))[lane]);
    float2 bb = ((const float2*)bias)[lane];
    float tx = fmaf(di, sf.x, ax);                // ax + di*h_self.x
    float ty = fmaf(di, sf.y, ay);
    float2 o;
    o.x = fmaxf(fmaf(di, tx, bb.x), 0.f);
    o.y = fmaxf(fmaf(di, ty, bb.y), 0.f);
    *(float2*)&x2buf[wave][2 * lane] = o;
    __syncthreads();

    // GEMM phase: waves 0-3, wave = col-frag c (16 cols each)
    if (threadIdx.x < 256) {
        int c = wave;
        int q = lane >> 4, lr = lane & 15;
        f32x4 g = (f32x4){0.f, 0.f, 0.f, 0.f};
#pragma unroll
        for (int s = 0; s < 4; s++) {
            const float* xp = &x2buf[lr][s * 32 + q * 8];
            float4 a0 = *(const float4*)xp;
            float4 a1 = *(const float4*)(xp + 4);
            float xv[8] = {a0.x, a0.y, a0.z, a0.w, a1.x, a1.y, a1.z, a1.w};
            bf16x8 a_hi, a_lo;
#pragma unroll
            for (int j = 0; j < 8; j++) {
                __bf16 h = (__bf16)xv[j];
                a_hi[j] = h;
                a_lo[j] = (__bf16)(xv[j] - (float)h);
            }
            size_t fo = (size_t)((c * 4 + s) * 64 + lane) * 8;
            bf16x8 bh = *(const bf16x8*)(w2hi + fo);
            bf16x8 bl = *(const bf16x8*)(w2lo + fo);
            g = __builtin_amdgcn_mfma_f32_16x16x32_bf16(a_hi, bh, g, 0, 0, 0);
            g = __builtin_amdgcn_mfma_f32_16x16x32_bf16(a_lo, bh, g, 0, 0, 0);
            g = __builtin_amdgcn_mfma_f32_16x16x32_bf16(a_hi, bl, g, 0, 0, 0);
        }
#pragma unroll
        for (int r = 0; r < 4; r++) {
            int grow = rb + q * 4 + r;
            hs2[(size_t)grow * 64 + c * 16 + lr] = __float2half(g[r] * dinv[grow]);
        }
    }
}

// ---------------- Aggregate CH=64: wave/node, uniform-row whole-wave gathers ------
// R20: padded trip count dp; 32-row super-bursts + 16-tail; ushort loads.
// hs2 rows pre-scaled by dinv (fused epilogue); sentinel row hs2[N]=0.
__global__ __launch_bounds__(256) void aggregate64_kernel(
        const __half* __restrict__ hs, const int* __restrict__ row_off,
        const int* __restrict__ deg, const int* __restrict__ ssrc,
        const float* __restrict__ dinv, const float* __restrict__ bias,
        float* __restrict__ out) {
    int node = (blockIdx.x * 256 + threadIdx.x) >> 6;
    int lane = threadIdx.x & 63;
    if (node >= N_NODES) return;
    int beg = __builtin_amdgcn_readfirstlane(row_off[node]);
    int d   = __builtin_amdgcn_readfirstlane(deg[node]);
    int dp  = (d + 15) & ~15;                     // PADDED trip count (R20 fix)
    float di = dinv[node];
    const char* Hb = (const char*)hs;             // row stride 128B
    float acc = 0.f;                              // lane owns channel `lane`

    for (int jj = 0; jj < dp; jj += 64) {
        int s_all = ssrc[beg + jj + lane];
        int jend = dp - jj; if (jend > 64) jend = 64;   // in {16,32,48,64}
        int done = 0;
        if (jend >= 32) {                         // super-burst 0
            unsigned short vv[32];
#pragma unroll
            for (int u = 0; u < 32; u++) {
                int su = __builtin_amdgcn_readlane(s_all, u);
                vv[u] = *(const unsigned short*)(Hb + (size_t)su * 128 + lane * 2);
            }
#pragma unroll
            for (int u = 0; u < 32; u++) acc += __half2float(*(const __half*)&vv[u]);
            done = 32;
            if (jend >= 64) {                     // super-burst 1
                unsigned short v2[32];
#pragma unroll
                for (int u = 0; u < 32; u++) {
                    int su = __builtin_amdgcn_readlane(s_all, 32 + u);
                    v2[u] = *(const unsigned short*)(Hb + (size_t)su * 128 + lane * 2);
                }
#pragma unroll
                for (int u = 0; u < 32; u++) acc += __half2float(*(const __half*)&v2[u]);
                done = 64;
            }
        }
        if (jend - done >= 16) {                  // 16-tail
            unsigned short vv[16];
#pragma unroll
            for (int u = 0; u < 16; u++) {
                int su = __builtin_amdgcn_readlane(s_all, done + u);
                vv[u] = *(const unsigned short*)(Hb + (size_t)su * 128 + lane * 2);
            }
#pragma unroll
            for (int u = 0; u < 16; u++) acc += __half2float(*(const __half*)&vv[u]);
        }
    }

    float sf = __half2float(((const __half*)(Hb + (size_t)node * 128))[lane]);
    out[(size_t)node * 64 + lane] = fmaf(di, acc + sf, bias[lane]);
}

// ---------------- launch ----------------

extern "C" void kernel_launch(void* const* d_in, const int* in_sizes, int n_in,
                              void* d_out, int out_size, void* d_ws, size_t ws_size,
                              hipStream_t stream) {
    const float* x  = (const float*)d_in[0];   // [N,128]
    const int*   ei = (const int*)d_in[1];     // [2,E]
    const float* W1 = (const float*)d_in[2];   // [128,128]
    const float* b1 = (const float*)d_in[3];   // [128]
    const float* W2 = (const float*)d_in[4];   // [128,64]
    const float* b2 = (const float*)d_in[5];   // [64]
    float* out = (float*)d_out;                // [N,64]

    const int* src = ei;
    const int* dst = ei + N_EDGES;

    char* p = (char*)d_ws;
    size_t off = 0;
    auto alloc = [&](size_t bytes) { void* q = p + off; off += (bytes + 255) & ~(size_t)255; return q; };
    float*    dinv    = (float*)   alloc((N_NODES + 1) * 4);  // +1 sentinel=0
    int*      deg     = (int*)     alloc(N_NODES * 4);
    int*      row_off = (int*)     alloc(N_NODES * 4);
    int*      gcur    = (int*)     alloc(NBIN * 4);
    int*      ssrc    = (int*)     alloc((size_t)NBIN * CAP2 * 4);  // 10.4 MB
    unsigned* ebin    = (unsigned*)alloc((size_t)NBIN * CAP * 4);   // 4.0 MB
    __bf16*   w1hi    = (__bf16*)  alloc(128 * 128 * 2);
    __bf16*   w1lo    = (__bf16*)  alloc(128 * 128 * 2);
    __bf16*   w2hi    = (__bf16*)  alloc(128 * 64 * 2);
    __bf16*   w2lo    = (__bf16*)  alloc(128 * 64 * 2);
    __half*   hs1     = (__half*)  alloc((size_t)(N_NODES + 1) * 128 * 2);
    __half*   hs2     = (__half*)  alloc((size_t)(N_NODES + 1) * 64 * 2);

    // 5 launches total
    prep_kernel<<<13, 256, 0, stream>>>(W1, W2, w1hi, w1lo, w2hi, w2lo, gcur,
                                        hs1, hs2, dinv);
    scatter_gemm_kernel<<<NB_SCAT + NB_GEMM, 256, 0, stream>>>(
        src, dst, gcur, ebin, x, w1hi, w1lo, hs1);
    bin_build_kernel<<<NBIN, 256, 0, stream>>>(ebin, gcur, deg, row_off, dinv, ssrc);

    fused_agg_gemm_kernel<<<N_NODES / 16, 1024, 0, stream>>>(
        hs1, row_off, deg, ssrc, dinv, b1, w2hi, w2lo, hs2);
    aggregate64_kernel<<<(N_NODES * 64 + 255) / 256, 256, 0, stream>>>(
        hs2, row_off, deg, ssrc, dinv, b2, out);
}

// Round 9
// 169.079 us; speedup vs baseline: 1.0261x; 1.0261x over previous
//
#include <hip/hip_runtime.h>
#include <hip/hip_fp16.h>

// GCN 2-layer: N=50000 nodes, E=800000 edges, 128 -> 128(relu) -> 64
// R21: ROLLBACK to R18 (best verified, 168.7us). R20 post-mortem: VGPR=32
//      proves the compiler register-minimized the 32-row super-burst into
//      small load/consume chunks (can't hold vv[32] in 32 VGPRs) -> waits
//      unchanged, SGPR 32->96, fused 43.5->45.9us, total +4.8us. Model
//      update: the 16-deep burst IS the depth the compiler will schedule as
//      outstanding; deeper software bursts don't become deeper hardware MLP
//      at -O3 (4th structural gather edit to lose: R13/R14/R15/R20).
// Evidence log: R2 MLP depth win; R4/R9 sliced layouts dead; R11 sentinel pad
// win; R12 fusion killed 51MB x2 trip; R13 spill catastrophe (min-waves cap +
// fat buffers); R14 shfl-idx ds_bpermute serialization; R15 branchy 2-node
// interleave dead; R16 uniform-row gather WIN (183.6->174.4; readlane ->
// scalar-base whole-wave row reads); R17 pad-16 neutral (rows down, waits up
// -> cancel); R18 chain compression WIN (175.0->168.7: dinv deferred via
// s_load, gemm1 merged into scatter launch); R19 edge-drop bug; R20 super-
// burst refused by compiler (VGPR=32). Harness poison fills (~44us each) own
// per-kernel top-5 -> judge by total.

#define N_NODES 50000
#define N_EDGES 800000
#define BINW    128
#define NBIN    391                    // ceil(50000/128)
#define CAP     2560                   // mean bin load 2046, ~11 sigma margin
#define CAP2    6656                   // padded: up to 2560 + 128*15 = 4480 fits
#define B_CHUNK 2048
#define NB_SCAT ((N_EDGES + B_CHUNK - 1) / B_CHUNK)   // 391
#define NB_GEMM ((N_NODES + 63) / 64)                 // 782

typedef __bf16 bf16x8 __attribute__((ext_vector_type(8)));
typedef float  f32x4  __attribute__((ext_vector_type(4)));

// ---------------- prep: W-frags, zero gcur, zero sentinel rows + dinv[N] ----------
template<int N>
__device__ inline void wprep_body(const float* __restrict__ W,
                                  __bf16* __restrict__ hi, __bf16* __restrict__ lo,
                                  int idx) {
    if (idx >= (N / 16) * 4 * 64) return;
    int l = idx & 63;
    int s = (idx >> 6) & 3;
    int c = idx >> 8;
    int n = c * 16 + (l & 15);
    int k0 = s * 32 + (l >> 4) * 8;
#pragma unroll
    for (int j = 0; j < 8; j++) {
        float w = W[(k0 + j) * N + n];
        __bf16 h = (__bf16)w;
        hi[idx * 8 + j] = h;
        lo[idx * 8 + j] = (__bf16)(w - (float)h);
    }
}

__global__ __launch_bounds__(256) void prep_kernel(
        const float* __restrict__ W1, const float* __restrict__ W2,
        __bf16* __restrict__ w1hi, __bf16* __restrict__ w1lo,
        __bf16* __restrict__ w2hi, __bf16* __restrict__ w2lo,
        int* __restrict__ gcur, __half* __restrict__ hs1, __half* __restrict__ hs2,
        float* __restrict__ dinv) {
    int b = blockIdx.x, tid = threadIdx.x;
    if (b < 8)       wprep_body<128>(W1, w1hi, w1lo, b * 256 + tid);
    else if (b < 12) wprep_body<64> (W2, w2hi, w2lo, (b - 8) * 256 + tid);
    else {
        for (int i = tid; i < NBIN; i += 256) gcur[i] = 0;
        if (tid < 128) hs1[(size_t)N_NODES * 128 + tid] = __float2half(0.f);
        if (tid < 64)  hs2[(size_t)N_NODES * 64 + tid] = __float2half(0.f);
        if (tid == 0)  dinv[N_NODES] = 0.f;       // sentinel weight (R18)
    }
}

// ---------------- MERGED: bin_scatter (blocks 0..390) || gemm1 (blocks 391..) -----

__device__ inline void bin_scatter_body(
        const int* __restrict__ src, const int* __restrict__ dst,
        int* __restrict__ gcur, unsigned* __restrict__ ebin) {
    __shared__ int cnt[512];
    __shared__ int boff[512];
    __shared__ int bcur[512];
    __shared__ int gbase[512];
    __shared__ unsigned stage[B_CHUNK];
    __shared__ int ex[256];
    int tid = threadIdx.x;
    int e0 = blockIdx.x * B_CHUNK;

    cnt[tid] = 0; cnt[tid + 256] = 0;
    __syncthreads();

    unsigned key[8]; int bins[8];
#pragma unroll
    for (int i = 0; i < 8; i++) {
        int e = e0 + tid + i * 256;               // coalesced
        if (e < N_EDGES) {
            int d = dst[e], s = src[e];
            key[i]  = ((unsigned)d << 16) | (unsigned)s;
            bins[i] = d >> 7;
            atomicAdd(&cnt[bins[i]], 1);
        } else bins[i] = -1;
    }
    __syncthreads();

    // exclusive scan of 512 bin counts with 256 threads (2 bins each)
    int a = cnt[2 * tid], b = cnt[2 * tid + 1];
    ex[tid] = a + b;
    __syncthreads();
    for (int off = 1; off < 256; off <<= 1) {
        int t = (tid >= off) ? ex[tid - off] : 0;
        __syncthreads();
        ex[tid] += t;
        __syncthreads();
    }
    int myex = ex[tid] - (a + b);
    boff[2 * tid] = myex;     boff[2 * tid + 1] = myex + a;
    bcur[2 * tid] = myex;     bcur[2 * tid + 1] = myex + a;
    __syncthreads();

    // compact into bin-contiguous staging
#pragma unroll
    for (int i = 0; i < 8; i++) {
        if (bins[i] >= 0) {
            int p = atomicAdd(&bcur[bins[i]], 1);
            stage[p] = key[i];
        }
    }

    // bulk-reserve global bin space (one atomic per non-empty (block,bin))
    __syncthreads();
    for (int b2 = tid; b2 < NBIN; b2 += 256) {
        int c = cnt[b2];
        gbase[b2] = (c > 0) ? atomicAdd(&gcur[b2], c) : 0;
    }
    __syncthreads();

    int total = N_EDGES - e0; if (total > B_CHUNK) total = B_CHUNK;
    for (int i = tid; i < total; i += 256) {
        unsigned k = stage[i];
        int bin = (int)(k >> 23);                 // dst>>7
        int idx = gbase[bin] + (i - boff[bin]);
        if (idx < CAP) ebin[(size_t)bin * CAP + idx] = k;  // guard (11-sigma)
    }
}

// gemm1 body: hs1[row][128] = fp16( (X@W1)[row] )  — UNSCALED (R18 defer)
__device__ inline void gemm_mfma128_body(
        int gb, const float* __restrict__ X, const __bf16* __restrict__ Whi,
        const __bf16* __restrict__ Wlo, __half* __restrict__ hs) {
    constexpr int NC = 8;
    int tid = threadIdx.x;
    int w = tid >> 6, lane = tid & 63;
    int q = lane >> 4, lr = lane & 15;
    int rb = gb * 64 + w * 16;
    int row = rb + lr;
    int rowc = (row < N_NODES) ? row : (N_NODES - 1);

    f32x4 acc[NC];
#pragma unroll
    for (int c = 0; c < NC; c++) acc[c] = (f32x4){0.f, 0.f, 0.f, 0.f};

#pragma unroll
    for (int s = 0; s < 4; s++) {
        const float* xp = X + (size_t)rowc * 128 + s * 32 + q * 8;
        float4 x0 = *(const float4*)xp;
        float4 x1 = *(const float4*)(xp + 4);
        float xv[8] = {x0.x, x0.y, x0.z, x0.w, x1.x, x1.y, x1.z, x1.w};
        bf16x8 a_hi, a_lo;
#pragma unroll
        for (int j = 0; j < 8; j++) {
            __bf16 h = (__bf16)xv[j];
            a_hi[j] = h;
            a_lo[j] = (__bf16)(xv[j] - (float)h);
        }
#pragma unroll
        for (int c = 0; c < NC; c++) {
            size_t fo = (size_t)((c * 4 + s) * 64 + lane) * 8;
            bf16x8 bh = *(const bf16x8*)(Whi + fo);
            bf16x8 bl = *(const bf16x8*)(Wlo + fo);
            acc[c] = __builtin_amdgcn_mfma_f32_16x16x32_bf16(a_hi, bh, acc[c], 0, 0, 0);
            acc[c] = __builtin_amdgcn_mfma_f32_16x16x32_bf16(a_lo, bh, acc[c], 0, 0, 0);
            acc[c] = __builtin_amdgcn_mfma_f32_16x16x32_bf16(a_hi, bl, acc[c], 0, 0, 0);
        }
    }

    // C/D layout: col = c*16 + lr, row(within 16) = q*4 + r
#pragma unroll
    for (int r = 0; r < 4; r++) {
        int grow = rb + q * 4 + r;
        if (grow < N_NODES) {
#pragma unroll
            for (int c = 0; c < NC; c++) {
                hs[(size_t)grow * 128 + c * 16 + lr] = __float2half(acc[c][r]);
            }
        }
    }
}

__global__ __launch_bounds__(256) void scatter_gemm_kernel(
        const int* __restrict__ src, const int* __restrict__ dst,
        int* __restrict__ gcur, unsigned* __restrict__ ebin,
        const float* __restrict__ X, const __bf16* __restrict__ Whi,
        const __bf16* __restrict__ Wlo, __half* __restrict__ hs1) {
    if (blockIdx.x < NB_SCAT) bin_scatter_body(src, dst, gcur, ebin);
    else gemm_mfma128_body(blockIdx.x - NB_SCAT, X, Whi, Wlo, hs1);
}

// ---------------- bin_build: histogram + padded scan + sentinel fill ---------------
// pad-16; sentinel prefill int4-vectorized.
__global__ __launch_bounds__(256) void bin_build_kernel(
        const unsigned* __restrict__ ebin, const int* __restrict__ gcur,
        int* __restrict__ deg, int* __restrict__ row_off,
        float* __restrict__ dinv, int* __restrict__ ssrc) {
    __shared__ int dl[BINW];
    __shared__ int pref[BINW];
    __shared__ int cur[BINW];
    __shared__ int padTotal;
    int bin = blockIdx.x, tid = threadIdx.x;
    if (tid < BINW) dl[tid] = 0;
    __syncthreads();
    int cnt = gcur[bin]; if (cnt > CAP) cnt = CAP;
    const unsigned* eb = ebin + (size_t)bin * CAP;
    for (int i = tid; i < cnt; i += 256)
        atomicAdd(&dl[(eb[i] >> 16) & 127], 1);
    __syncthreads();
    // Hillis-Steele inclusive scan over 128 PADDED counts (pad-16)
    int pc = 0;
    if (tid < BINW) { pc = (dl[tid] + 15) & ~15; pref[tid] = pc; }
    __syncthreads();
    for (int off = 1; off < BINW; off <<= 1) {
        int t = 0;
        if (tid < BINW && tid >= off) t = pref[tid - off];
        __syncthreads();
        if (tid < BINW) pref[tid] += t;
        __syncthreads();
    }
    if (tid < BINW) {
        int ex = pref[tid] - pc;                  // padded exclusive prefix
        cur[tid] = ex;
        int node = bin * BINW + tid;
        if (node < N_NODES) {
            deg[node]     = dl[tid];
            row_off[node] = bin * CAP2 + ex;
            dinv[node]    = rsqrtf((float)(dl[tid] + 1));   // +1 self-loop
        }
        if (tid == BINW - 1) padTotal = pref[tid];
    }
    __syncthreads();
    int pt4 = padTotal >> 2;                      // padTotal multiple of 16
    int4* sb4 = (int4*)(ssrc + (size_t)bin * CAP2);
    int4 sent = make_int4(N_NODES, N_NODES, N_NODES, N_NODES);
    for (int i = tid; i < pt4; i += 256) sb4[i] = sent;     // sentinel prefill
    __syncthreads();
    int* sb = ssrc + (size_t)bin * CAP2;
    for (int i = tid; i < cnt; i += 256) {
        unsigned k = eb[i];
        int p = atomicAdd(&cur[(k >> 16) & 127], 1);
        sb[p] = (int)(k & 0xFFFFu);
    }
}

// ---------------- FUSED: agg128(+relu) -> LDS x2 rows -> 16x64 MFMA -> hs2 --------
// block = 1024 thr = 16 waves = 16 nodes (50000 = 3125*16 exact).
// R18 gather (restored): bursts of 16 uniform rows (pad-16). One s_all idx
// load per 64 edges -> readlane -> scalar-base whole-wave 256B row reads.
// Per-row weight dinv[su] (s_load, scalar pipe) since hs1 is unscaled.
__global__ __launch_bounds__(1024) void fused_agg_gemm_kernel(
        const __half* __restrict__ hs1, const int* __restrict__ row_off,
        const int* __restrict__ deg, const int* __restrict__ ssrc,
        const float* __restrict__ dinv, const float* __restrict__ bias,
        const __bf16* __restrict__ w2hi, const __bf16* __restrict__ w2lo,
        __half* __restrict__ hs2) {
    __shared__ float x2buf[16][132];              // pad 132: 2-way banks (free)
    int wave = threadIdx.x >> 6;
    int lane = threadIdx.x & 63;
    int rb = blockIdx.x * 16;
    int node = rb + wave;                         // always < N_NODES

    int beg = __builtin_amdgcn_readfirstlane(row_off[node]);
    int d   = __builtin_amdgcn_readfirstlane(deg[node]);
    float di = dinv[node];
    const char* Hb = (const char*)hs1;            // row stride 256B
    float ax = 0.f, ay = 0.f;                     // lane owns ch 2*lane, 2*lane+1

    for (int jj = 0; jj < d; jj += 64) {          // 64 edges per idx load
        int s_all = ssrc[beg + jj + lane];        // coalesced; span padded-16
        int jend = d - jj; if (jend > 64) jend = 64;
#pragma unroll
        for (int b = 0; b < 4; b++) {
            if (b * 16 < jend) {                  // wave-uniform (d uniform)
                unsigned vv[16]; float ws[16];
#pragma unroll
                for (int u = 0; u < 16; u++) {
                    int su = __builtin_amdgcn_readlane(s_all, b * 16 + u);
                    vv[u] = *(const unsigned*)(Hb + (size_t)su * 256 + lane * 4);
                    ws[u] = dinv[su];             // uniform -> s_load (scalar pipe)
                }
#pragma unroll
                for (int u = 0; u < 16; u++) {
                    float2 f = __half22float2(*(const __half2*)&vv[u]);
                    ax = fmaf(ws[u], f.x, ax);
                    ay = fmaf(ws[u], f.y, ay);
                }
            }
        }
    }

    // epilogue: self-loop (di^2 * h[node]) + bias + relu, per-lane ch pair
    float2 sf = __half22float2(((const __half2*)(Hb + (size_t)node * 256))[lane]);
    float2 bb = ((const float2*)bias)[lane];
    float tx = fmaf(di, sf.x, ax);                // ax + di*h_self.x
    float ty = fmaf(di, sf.y, ay);
    float2 o;
    o.x = fmaxf(fmaf(di, tx, bb.x), 0.f);
    o.y = fmaxf(fmaf(di, ty, bb.y), 0.f);
    *(float2*)&x2buf[wave][2 * lane] = o;
    __syncthreads();

    // GEMM phase: waves 0-3, wave = col-frag c (16 cols each)
    if (threadIdx.x < 256) {
        int c = wave;
        int q = lane >> 4, lr = lane & 15;
        f32x4 g = (f32x4){0.f, 0.f, 0.f, 0.f};
#pragma unroll
        for (int s = 0; s < 4; s++) {
            const float* xp = &x2buf[lr][s * 32 + q * 8];
            float4 a0 = *(const float4*)xp;
            float4 a1 = *(const float4*)(xp + 4);
            float xv[8] = {a0.x, a0.y, a0.z, a0.w, a1.x, a1.y, a1.z, a1.w};
            bf16x8 a_hi, a_lo;
#pragma unroll
            for (int j = 0; j < 8; j++) {
                __bf16 h = (__bf16)xv[j];
                a_hi[j] = h;
                a_lo[j] = (__bf16)(xv[j] - (float)h);
            }
            size_t fo = (size_t)((c * 4 + s) * 64 + lane) * 8;
            bf16x8 bh = *(const bf16x8*)(w2hi + fo);
            bf16x8 bl = *(const bf16x8*)(w2lo + fo);
            g = __builtin_amdgcn_mfma_f32_16x16x32_bf16(a_hi, bh, g, 0, 0, 0);
            g = __builtin_amdgcn_mfma_f32_16x16x32_bf16(a_lo, bh, g, 0, 0, 0);
            g = __builtin_amdgcn_mfma_f32_16x16x32_bf16(a_hi, bl, g, 0, 0, 0);
        }
#pragma unroll
        for (int r = 0; r < 4; r++) {
            int grow = rb + q * 4 + r;
            hs2[(size_t)grow * 64 + c * 16 + lr] = __float2half(g[r] * dinv[grow]);
        }
    }
}

// ---------------- Aggregate CH=64: wave/node, uniform-row whole-wave gathers ------
// R18 (restored): bursts of 16 uniform rows (pad-16); ushort loads.
// hs2 rows pre-scaled by dinv (fused epilogue) -> no per-row weight here.
__global__ __launch_bounds__(256) void aggregate64_kernel(
        const __half* __restrict__ hs, const int* __restrict__ row_off,
        const int* __restrict__ deg, const int* __restrict__ ssrc,
        const float* __restrict__ dinv, const float* __restrict__ bias,
        float* __restrict__ out) {
    int node = (blockIdx.x * 256 + threadIdx.x) >> 6;
    int lane = threadIdx.x & 63;
    if (node >= N_NODES) return;
    int beg = __builtin_amdgcn_readfirstlane(row_off[node]);
    int d   = __builtin_amdgcn_readfirstlane(deg[node]);
    float di = dinv[node];
    const char* Hb = (const char*)hs;             // row stride 128B
    float acc = 0.f;                              // lane owns channel `lane`

    for (int jj = 0; jj < d; jj += 64) {
        int s_all = ssrc[beg + jj + lane];
        int jend = d - jj; if (jend > 64) jend = 64;
#pragma unroll
        for (int b = 0; b < 4; b++) {
            if (b * 16 < jend) {
                unsigned short vv[16];
#pragma unroll
                for (int u = 0; u < 16; u++) {
                    int su = __builtin_amdgcn_readlane(s_all, b * 16 + u);
                    vv[u] = *(const unsigned short*)(Hb + (size_t)su * 128 + lane * 2);
                }
#pragma unroll
                for (int u = 0; u < 16; u++) {
                    acc += __half2float(*(const __half*)&vv[u]);
                }
            }
        }
    }

    float sf = __half2float(((const __half*)(Hb + (size_t)node * 128))[lane]);
    out[(size_t)node * 64 + lane] = fmaf(di, acc + sf, bias[lane]);
}

// ---------------- launch ----------------

extern "C" void kernel_launch(void* const* d_in, const int* in_sizes, int n_in,
                              void* d_out, int out_size, void* d_ws, size_t ws_size,
                              hipStream_t stream) {
    const float* x  = (const float*)d_in[0];   // [N,128]
    const int*   ei = (const int*)d_in[1];     // [2,E]
    const float* W1 = (const float*)d_in[2];   // [128,128]
    const float* b1 = (const float*)d_in[3];   // [128]
    const float* W2 = (const float*)d_in[4];   // [128,64]
    const float* b2 = (const float*)d_in[5];   // [64]
    float* out = (float*)d_out;                // [N,64]

    const int* src = ei;
    const int* dst = ei + N_EDGES;

    char* p = (char*)d_ws;
    size_t off = 0;
    auto alloc = [&](size_t bytes) { void* q = p + off; off += (bytes + 255) & ~(size_t)255; return q; };
    float*    dinv    = (float*)   alloc((N_NODES + 1) * 4);  // +1 sentinel=0
    int*      deg     = (int*)     alloc(N_NODES * 4);
    int*      row_off = (int*)     alloc(N_NODES * 4);
    int*      gcur    = (int*)     alloc(NBIN * 4);
    int*      ssrc    = (int*)     alloc((size_t)NBIN * CAP2 * 4);  // 10.4 MB
    unsigned* ebin    = (unsigned*)alloc((size_t)NBIN * CAP * 4);   // 4.0 MB
    __bf16*   w1hi    = (__bf16*)  alloc(128 * 128 * 2);
    __bf16*   w1lo    = (__bf16*)  alloc(128 * 128 * 2);
    __bf16*   w2hi    = (__bf16*)  alloc(128 * 64 * 2);
    __bf16*   w2lo    = (__bf16*)  alloc(128 * 64 * 2);
    __half*   hs1     = (__half*)  alloc((size_t)(N_NODES + 1) * 128 * 2);
    __half*   hs2     = (__half*)  alloc((size_t)(N_NODES + 1) * 64 * 2);

    // 5 launches total
    prep_kernel<<<13, 256, 0, stream>>>(W1, W2, w1hi, w1lo, w2hi, w2lo, gcur,
                                        hs1, hs2, dinv);
    scatter_gemm_kernel<<<NB_SCAT + NB_GEMM, 256, 0, stream>>>(
        src, dst, gcur, ebin, x, w1hi, w1lo, hs1);
    bin_build_kernel<<<NBIN, 256, 0, stream>>>(ebin, gcur, deg, row_off, dinv, ssrc);

    fused_agg_gemm_kernel<<<N_NODES / 16, 1024, 0, stream>>>(
        hs1, row_off, deg, ssrc, dinv, b1, w2hi, w2lo, hs2);
    aggregate64_kernel<<<(N_NODES * 64 + 255) / 256, 256, 0, stream>>>(
        hs2, row_off, deg, ssrc, dinv, b2, out);
}

// Round 10
// 164.597 us; speedup vs baseline: 1.0540x; 1.0272x over previous
//
#include <hip/hip_runtime.h>
#include <hip/hip_fp16.h>

// GCN 2-layer: N=50000 nodes, E=800000 edges, 128 -> 128(relu) -> 64
// R22: mid-chain compression, part 2. R21 rollback verified 169.1us (=R18).
//      Observation across R12..R21 profiles: fused stuck at 42-45us through
//      FIVE gather restructures -> latency/scheduling regime not movable at
//      HIP source level; kernel closed. Remaining movable serial time:
//      [scatter||gemm](~10) -> build(~8). gemm1 is block-divisible and build
//      depends only on the scatter half -> split gemm 50/50:
//        launch A: scatter(391) || gemm[0..390]   ~max(5,5)=5us
//        launch B: build(391)  || gemm[391..781]  ~max(8,5)=8us
//      hs1 complete before fused (A,B both precede it); build blocks are
//      first in B's dispatch order. Single-variable change.
// Evidence log: R2 MLP depth win; R4/R9 sliced layouts dead; R11 sentinel pad
// win; R12 fusion killed 51MB x2 trip; R13 spill catastrophe (min-waves cap +
// fat buffers); R14 shfl-idx ds_bpermute serialization; R15 branchy 2-node
// interleave dead; R16 uniform-row gather WIN (183.6->174.4; readlane ->
// scalar-base whole-wave row reads); R17 pad-16 neutral; R18 chain
// compression WIN (175.0->168.7: dinv deferred via s_load, gemm1 merged into
// scatter launch); R19 edge-drop bug; R20 super-burst refused by compiler
// (VGPR=32); R21 rollback verified. Harness poison fills (~44us each) own
// per-kernel top-5 -> judge by total.

#define N_NODES 50000
#define N_EDGES 800000
#define BINW    128
#define NBIN    391                    // ceil(50000/128)
#define CAP     2560                   // mean bin load 2046, ~11 sigma margin
#define CAP2    6656                   // padded: up to 2560 + 128*15 = 4480 fits
#define B_CHUNK 2048
#define NB_SCAT ((N_EDGES + B_CHUNK - 1) / B_CHUNK)   // 391
#define NB_GEMM ((N_NODES + 63) / 64)                 // 782
#define G_A     391                    // gemm blocks co-launched with scatter
#define G_B     (NB_GEMM - G_A)        // gemm blocks co-launched with build

typedef __bf16 bf16x8 __attribute__((ext_vector_type(8)));
typedef float  f32x4  __attribute__((ext_vector_type(4)));

// ---------------- prep: W-frags, zero gcur, zero sentinel rows + dinv[N] ----------
template<int N>
__device__ inline void wprep_body(const float* __restrict__ W,
                                  __bf16* __restrict__ hi, __bf16* __restrict__ lo,
                                  int idx) {
    if (idx >= (N / 16) * 4 * 64) return;
    int l = idx & 63;
    int s = (idx >> 6) & 3;
    int c = idx >> 8;
    int n = c * 16 + (l & 15);
    int k0 = s * 32 + (l >> 4) * 8;
#pragma unroll
    for (int j = 0; j < 8; j++) {
        float w = W[(k0 + j) * N + n];
        __bf16 h = (__bf16)w;
        hi[idx * 8 + j] = h;
        lo[idx * 8 + j] = (__bf16)(w - (float)h);
    }
}

__global__ __launch_bounds__(256) void prep_kernel(
        const float* __restrict__ W1, const float* __restrict__ W2,
        __bf16* __restrict__ w1hi, __bf16* __restrict__ w1lo,
        __bf16* __restrict__ w2hi, __bf16* __restrict__ w2lo,
        int* __restrict__ gcur, __half* __restrict__ hs1, __half* __restrict__ hs2,
        float* __restrict__ dinv) {
    int b = blockIdx.x, tid = threadIdx.x;
    if (b < 8)       wprep_body<128>(W1, w1hi, w1lo, b * 256 + tid);
    else if (b < 12) wprep_body<64> (W2, w2hi, w2lo, (b - 8) * 256 + tid);
    else {
        for (int i = tid; i < NBIN; i += 256) gcur[i] = 0;
        if (tid < 128) hs1[(size_t)N_NODES * 128 + tid] = __float2half(0.f);
        if (tid < 64)  hs2[(size_t)N_NODES * 64 + tid] = __float2half(0.f);
        if (tid == 0)  dinv[N_NODES] = 0.f;       // sentinel weight (R18)
    }
}

// ---------------- bodies: scatter, gemm1, build ----------------

__device__ inline void bin_scatter_body(
        const int* __restrict__ src, const int* __restrict__ dst,
        int* __restrict__ gcur, unsigned* __restrict__ ebin) {
    __shared__ int cnt[512];
    __shared__ int boff[512];
    __shared__ int bcur[512];
    __shared__ int gbase[512];
    __shared__ unsigned stage[B_CHUNK];
    __shared__ int ex[256];
    int tid = threadIdx.x;
    int e0 = blockIdx.x * B_CHUNK;

    cnt[tid] = 0; cnt[tid + 256] = 0;
    __syncthreads();

    unsigned key[8]; int bins[8];
#pragma unroll
    for (int i = 0; i < 8; i++) {
        int e = e0 + tid + i * 256;               // coalesced
        if (e < N_EDGES) {
            int d = dst[e], s = src[e];
            key[i]  = ((unsigned)d << 16) | (unsigned)s;
            bins[i] = d >> 7;
            atomicAdd(&cnt[bins[i]], 1);
        } else bins[i] = -1;
    }
    __syncthreads();

    // exclusive scan of 512 bin counts with 256 threads (2 bins each)
    int a = cnt[2 * tid], b = cnt[2 * tid + 1];
    ex[tid] = a + b;
    __syncthreads();
    for (int off = 1; off < 256; off <<= 1) {
        int t = (tid >= off) ? ex[tid - off] : 0;
        __syncthreads();
        ex[tid] += t;
        __syncthreads();
    }
    int myex = ex[tid] - (a + b);
    boff[2 * tid] = myex;     boff[2 * tid + 1] = myex + a;
    bcur[2 * tid] = myex;     bcur[2 * tid + 1] = myex + a;
    __syncthreads();

    // compact into bin-contiguous staging
#pragma unroll
    for (int i = 0; i < 8; i++) {
        if (bins[i] >= 0) {
            int p = atomicAdd(&bcur[bins[i]], 1);
            stage[p] = key[i];
        }
    }

    // bulk-reserve global bin space (one atomic per non-empty (block,bin))
    __syncthreads();
    for (int b2 = tid; b2 < NBIN; b2 += 256) {
        int c = cnt[b2];
        gbase[b2] = (c > 0) ? atomicAdd(&gcur[b2], c) : 0;
    }
    __syncthreads();

    int total = N_EDGES - e0; if (total > B_CHUNK) total = B_CHUNK;
    for (int i = tid; i < total; i += 256) {
        unsigned k = stage[i];
        int bin = (int)(k >> 23);                 // dst>>7
        int idx = gbase[bin] + (i - boff[bin]);
        if (idx < CAP) ebin[(size_t)bin * CAP + idx] = k;  // guard (11-sigma)
    }
}

// gemm1 body: hs1[row][128] = fp16( (X@W1)[row] )  — UNSCALED (R18 defer)
__device__ inline void gemm_mfma128_body(
        int gb, const float* __restrict__ X, const __bf16* __restrict__ Whi,
        const __bf16* __restrict__ Wlo, __half* __restrict__ hs) {
    constexpr int NC = 8;
    int tid = threadIdx.x;
    int w = tid >> 6, lane = tid & 63;
    int q = lane >> 4, lr = lane & 15;
    int rb = gb * 64 + w * 16;
    int row = rb + lr;
    int rowc = (row < N_NODES) ? row : (N_NODES - 1);

    f32x4 acc[NC];
#pragma unroll
    for (int c = 0; c < NC; c++) acc[c] = (f32x4){0.f, 0.f, 0.f, 0.f};

#pragma unroll
    for (int s = 0; s < 4; s++) {
        const float* xp = X + (size_t)rowc * 128 + s * 32 + q * 8;
        float4 x0 = *(const float4*)xp;
        float4 x1 = *(const float4*)(xp + 4);
        float xv[8] = {x0.x, x0.y, x0.z, x0.w, x1.x, x1.y, x1.z, x1.w};
        bf16x8 a_hi, a_lo;
#pragma unroll
        for (int j = 0; j < 8; j++) {
            __bf16 h = (__bf16)xv[j];
            a_hi[j] = h;
            a_lo[j] = (__bf16)(xv[j] - (float)h);
        }
#pragma unroll
        for (int c = 0; c < NC; c++) {
            size_t fo = (size_t)((c * 4 + s) * 64 + lane) * 8;
            bf16x8 bh = *(const bf16x8*)(Whi + fo);
            bf16x8 bl = *(const bf16x8*)(Wlo + fo);
            acc[c] = __builtin_amdgcn_mfma_f32_16x16x32_bf16(a_hi, bh, acc[c], 0, 0, 0);
            acc[c] = __builtin_amdgcn_mfma_f32_16x16x32_bf16(a_lo, bh, acc[c], 0, 0, 0);
            acc[c] = __builtin_amdgcn_mfma_f32_16x16x32_bf16(a_hi, bl, acc[c], 0, 0, 0);
        }
    }

    // C/D layout: col = c*16 + lr, row(within 16) = q*4 + r
#pragma unroll
    for (int r = 0; r < 4; r++) {
        int grow = rb + q * 4 + r;
        if (grow < N_NODES) {
#pragma unroll
            for (int c = 0; c < NC; c++) {
                hs[(size_t)grow * 128 + c * 16 + lr] = __float2half(acc[c][r]);
            }
        }
    }
}

// bin_build body: histogram + padded scan (pad-16) + sentinel fill
__device__ inline void bin_build_body(
        int bin, const unsigned* __restrict__ ebin, const int* __restrict__ gcur,
        int* __restrict__ deg, int* __restrict__ row_off,
        float* __restrict__ dinv, int* __restrict__ ssrc) {
    __shared__ int dl[BINW];
    __shared__ int pref[BINW];
    __shared__ int cur[BINW];
    __shared__ int padTotal;
    int tid = threadIdx.x;
    if (tid < BINW) dl[tid] = 0;
    __syncthreads();
    int cnt = gcur[bin]; if (cnt > CAP) cnt = CAP;
    const unsigned* eb = ebin + (size_t)bin * CAP;
    for (int i = tid; i < cnt; i += 256)
        atomicAdd(&dl[(eb[i] >> 16) & 127], 1);
    __syncthreads();
    // Hillis-Steele inclusive scan over 128 PADDED counts (pad-16)
    int pc = 0;
    if (tid < BINW) { pc = (dl[tid] + 15) & ~15; pref[tid] = pc; }
    __syncthreads();
    for (int off = 1; off < BINW; off <<= 1) {
        int t = 0;
        if (tid < BINW && tid >= off) t = pref[tid - off];
        __syncthreads();
        if (tid < BINW) pref[tid] += t;
        __syncthreads();
    }
    if (tid < BINW) {
        int ex = pref[tid] - pc;                  // padded exclusive prefix
        cur[tid] = ex;
        int node = bin * BINW + tid;
        if (node < N_NODES) {
            deg[node]     = dl[tid];
            row_off[node] = bin * CAP2 + ex;
            dinv[node]    = rsqrtf((float)(dl[tid] + 1));   // +1 self-loop
        }
        if (tid == BINW - 1) padTotal = pref[tid];
    }
    __syncthreads();
    int pt4 = padTotal >> 2;                      // padTotal multiple of 16
    int4* sb4 = (int4*)(ssrc + (size_t)bin * CAP2);
    int4 sent = make_int4(N_NODES, N_NODES, N_NODES, N_NODES);
    for (int i = tid; i < pt4; i += 256) sb4[i] = sent;     // sentinel prefill
    __syncthreads();
    int* sb = ssrc + (size_t)bin * CAP2;
    for (int i = tid; i < cnt; i += 256) {
        unsigned k = eb[i];
        int p = atomicAdd(&cur[(k >> 16) & 127], 1);
        sb[p] = (int)(k & 0xFFFFu);
    }
}

// ---------------- launch A: scatter (0..390) || gemm1 blocks [0, G_A) --------------
__global__ __launch_bounds__(256) void scatter_gemm_kernel(
        const int* __restrict__ src, const int* __restrict__ dst,
        int* __restrict__ gcur, unsigned* __restrict__ ebin,
        const float* __restrict__ X, const __bf16* __restrict__ Whi,
        const __bf16* __restrict__ Wlo, __half* __restrict__ hs1) {
    if (blockIdx.x < NB_SCAT) bin_scatter_body(src, dst, gcur, ebin);
    else gemm_mfma128_body(blockIdx.x - NB_SCAT, X, Whi, Wlo, hs1);
}

// ---------------- launch B: build (0..390) || gemm1 blocks [G_A, NB_GEMM) ---------
__global__ __launch_bounds__(256) void build_gemm_kernel(
        const unsigned* __restrict__ ebin, const int* __restrict__ gcur,
        int* __restrict__ deg, int* __restrict__ row_off,
        float* __restrict__ dinv, int* __restrict__ ssrc,
        const float* __restrict__ X, const __bf16* __restrict__ Whi,
        const __bf16* __restrict__ Wlo, __half* __restrict__ hs1) {
    if (blockIdx.x < NBIN)
        bin_build_body(blockIdx.x, ebin, gcur, deg, row_off, dinv, ssrc);
    else
        gemm_mfma128_body(G_A + (int)blockIdx.x - NBIN, X, Whi, Wlo, hs1);
}

// ---------------- FUSED: agg128(+relu) -> LDS x2 rows -> 16x64 MFMA -> hs2 --------
// block = 1024 thr = 16 waves = 16 nodes (50000 = 3125*16 exact).
// R18 gather: bursts of 16 uniform rows (pad-16). One s_all idx load per 64
// edges -> readlane -> scalar-base whole-wave 256B row reads. Per-row weight
// dinv[su] (s_load, scalar pipe) since hs1 is unscaled.
__global__ __launch_bounds__(1024) void fused_agg_gemm_kernel(
        const __half* __restrict__ hs1, const int* __restrict__ row_off,
        const int* __restrict__ deg, const int* __restrict__ ssrc,
        const float* __restrict__ dinv, const float* __restrict__ bias,
        const __bf16* __restrict__ w2hi, const __bf16* __restrict__ w2lo,
        __half* __restrict__ hs2) {
    __shared__ float x2buf[16][132];              // pad 132: 2-way banks (free)
    int wave = threadIdx.x >> 6;
    int lane = threadIdx.x & 63;
    int rb = blockIdx.x * 16;
    int node = rb + wave;                         // always < N_NODES

    int beg = __builtin_amdgcn_readfirstlane(row_off[node]);
    int d   = __builtin_amdgcn_readfirstlane(deg[node]);
    float di = dinv[node];
    const char* Hb = (const char*)hs1;            // row stride 256B
    float ax = 0.f, ay = 0.f;                     // lane owns ch 2*lane, 2*lane+1

    for (int jj = 0; jj < d; jj += 64) {          // 64 edges per idx load
        int s_all = ssrc[beg + jj + lane];        // coalesced; span padded-16
        int jend = d - jj; if (jend > 64) jend = 64;
#pragma unroll
        for (int b = 0; b < 4; b++) {
            if (b * 16 < jend) {                  // wave-uniform (d uniform)
                unsigned vv[16]; float ws[16];
#pragma unroll
                for (int u = 0; u < 16; u++) {
                    int su = __builtin_amdgcn_readlane(s_all, b * 16 + u);
                    vv[u] = *(const unsigned*)(Hb + (size_t)su * 256 + lane * 4);
                    ws[u] = dinv[su];             // uniform -> s_load (scalar pipe)
                }
#pragma unroll
                for (int u = 0; u < 16; u++) {
                    float2 f = __half22float2(*(const __half2*)&vv[u]);
                    ax = fmaf(ws[u], f.x, ax);
                    ay = fmaf(ws[u], f.y, ay);
                }
            }
        }
    }

    // epilogue: self-loop (di^2 * h[node]) + bias + relu, per-lane ch pair
    float2 sf = __half22float2(((const __half2*)(Hb + (size_t)node * 256))[lane]);
    float2 bb = ((const float2*)bias)[lane];
    float tx = fmaf(di, sf.x, ax);                // ax + di*h_self.x
    float ty = fmaf(di, sf.y, ay);
    float2 o;
    o.x = fmaxf(fmaf(di, tx, bb.x), 0.f);
    o.y = fmaxf(fmaf(di, ty, bb.y), 0.f);
    *(float2*)&x2buf[wave][2 * lane] = o;
    __syncthreads();

    // GEMM phase: waves 0-3, wave = col-frag c (16 cols each)
    if (threadIdx.x < 256) {
        int c = wave;
        int q = lane >> 4, lr = lane & 15;
        f32x4 g = (f32x4){0.f, 0.f, 0.f, 0.f};
#pragma unroll
        for (int s = 0; s < 4; s++) {
            const float* xp = &x2buf[lr][s * 32 + q * 8];
            float4 a0 = *(const float4*)xp;
            float4 a1 = *(const float4*)(xp + 4);
            float xv[8] = {a0.x, a0.y, a0.z, a0.w, a1.x, a1.y, a1.z, a1.w};
            bf16x8 a_hi, a_lo;
#pragma unroll
            for (int j = 0; j < 8; j++) {
                __bf16 h = (__bf16)xv[j];
                a_hi[j] = h;
                a_lo[j] = (__bf16)(xv[j] - (float)h);
            }
            size_t fo = (size_t)((c * 4 + s) * 64 + lane) * 8;
            bf16x8 bh = *(const bf16x8*)(w2hi + fo);
            bf16x8 bl = *(const bf16x8*)(w2lo + fo);
            g = __builtin_amdgcn_mfma_f32_16x16x32_bf16(a_hi, bh, g, 0, 0, 0);
            g = __builtin_amdgcn_mfma_f32_16x16x32_bf16(a_lo, bh, g, 0, 0, 0);
            g = __builtin_amdgcn_mfma_f32_16x16x32_bf16(a_hi, bl, g, 0, 0, 0);
        }
#pragma unroll
        for (int r = 0; r < 4; r++) {
            int grow = rb + q * 4 + r;
            hs2[(size_t)grow * 64 + c * 16 + lr] = __float2half(g[r] * dinv[grow]);
        }
    }
}

// ---------------- Aggregate CH=64: wave/node, uniform-row whole-wave gathers ------
// R18: bursts of 16 uniform rows (pad-16); ushort loads. hs2 rows pre-scaled
// by dinv (fused epilogue) -> no per-row weight here.
__global__ __launch_bounds__(256) void aggregate64_kernel(
        const __half* __restrict__ hs, const int* __restrict__ row_off,
        const int* __restrict__ deg, const int* __restrict__ ssrc,
        const float* __restrict__ dinv, const float* __restrict__ bias,
        float* __restrict__ out) {
    int node = (blockIdx.x * 256 + threadIdx.x) >> 6;
    int lane = threadIdx.x & 63;
    if (node >= N_NODES) return;
    int beg = __builtin_amdgcn_readfirstlane(row_off[node]);
    int d   = __builtin_amdgcn_readfirstlane(deg[node]);
    float di = dinv[node];
    const char* Hb = (const char*)hs;             // row stride 128B
    float acc = 0.f;                              // lane owns channel `lane`

    for (int jj = 0; jj < d; jj += 64) {
        int s_all = ssrc[beg + jj + lane];
        int jend = d - jj; if (jend > 64) jend = 64;
#pragma unroll
        for (int b = 0; b < 4; b++) {
            if (b * 16 < jend) {
                unsigned short vv[16];
#pragma unroll
                for (int u = 0; u < 16; u++) {
                    int su = __builtin_amdgcn_readlane(s_all, b * 16 + u);
                    vv[u] = *(const unsigned short*)(Hb + (size_t)su * 128 + lane * 2);
                }
#pragma unroll
                for (int u = 0; u < 16; u++) {
                    acc += __half2float(*(const __half*)&vv[u]);
                }
            }
        }
    }

    float sf = __half2float(((const __half*)(Hb + (size_t)node * 128))[lane]);
    out[(size_t)node * 64 + lane] = fmaf(di, acc + sf, bias[lane]);
}

// ---------------- launch ----------------

extern "C" void kernel_launch(void* const* d_in, const int* in_sizes, int n_in,
                              void* d_out, int out_size, void* d_ws, size_t ws_size,
                              hipStream_t stream) {
    const float* x  = (const float*)d_in[0];   // [N,128]
    const int*   ei = (const int*)d_in[1];     // [2,E]
    const float* W1 = (const float*)d_in[2];   // [128,128]
    const float* b1 = (const float*)d_in[3];   // [128]
    const float* W2 = (const float*)d_in[4];   // [128,64]
    const float* b2 = (const float*)d_in[5];   // [64]
    float* out = (float*)d_out;                // [N,64]

    const int* src = ei;
    const int* dst = ei + N_EDGES;

    char* p = (char*)d_ws;
    size_t off = 0;
    auto alloc = [&](size_t bytes) { void* q = p + off; off += (bytes + 255) & ~(size_t)255; return q; };
    float*    dinv    = (float*)   alloc((N_NODES + 1) * 4);  // +1 sentinel=0
    int*      deg     = (int*)     alloc(N_NODES * 4);
    int*      row_off = (int*)     alloc(N_NODES * 4);
    int*      gcur    = (int*)     alloc(NBIN * 4);
    int*      ssrc    = (int*)     alloc((size_t)NBIN * CAP2 * 4);  // 10.4 MB
    unsigned* ebin    = (unsigned*)alloc((size_t)NBIN * CAP * 4);   // 4.0 MB
    __bf16*   w1hi    = (__bf16*)  alloc(128 * 128 * 2);
    __bf16*   w1lo    = (__bf16*)  alloc(128 * 128 * 2);
    __bf16*   w2hi    = (__bf16*)  alloc(128 * 64 * 2);
    __bf16*   w2lo    = (__bf16*)  alloc(128 * 64 * 2);
    __half*   hs1     = (__half*)  alloc((size_t)(N_NODES + 1) * 128 * 2);
    __half*   hs2     = (__half*)  alloc((size_t)(N_NODES + 1) * 64 * 2);

    // 5 launches total
    prep_kernel<<<13, 256, 0, stream>>>(W1, W2, w1hi, w1lo, w2hi, w2lo, gcur,
                                        hs1, hs2, dinv);
    scatter_gemm_kernel<<<NB_SCAT + G_A, 256, 0, stream>>>(
        src, dst, gcur, ebin, x, w1hi, w1lo, hs1);
    build_gemm_kernel<<<NBIN + G_B, 256, 0, stream>>>(
        ebin, gcur, deg, row_off, dinv, ssrc, x, w1hi, w1lo, hs1);

    fused_agg_gemm_kernel<<<N_NODES / 16, 1024, 0, stream>>>(
        hs1, row_off, deg, ssrc, dinv, b1, w2hi, w2lo, hs2);
    aggregate64_kernel<<<(N_NODES * 64 + 255) / 256, 256, 0, stream>>>(
        hs2, row_off, deg, ssrc, dinv, b2, out);
}